// Round 1
// baseline (528.354 us; speedup 1.0000x reference)
//
#include <hip/hip_runtime.h>
#include <stdint.h>

// softmax((x@q)@(x@k)) @ (x@v), N=2048, fp32 in/out.
// R6: replace reg-staged LDS staging (global->VGPR->ds_write) with direct
// __builtin_amdgcn_global_load_lds width=16 (m151: +35% at this exact 128^2
// double-buffered structure). Per step: barrier (compiler drains vmcnt ->
// buf[p] ready); ds_read frags from buf[p]; issue 8 glds into buf[1-p]
// (hidden under the 48-MFMA region, drained at next barrier); MFMA.
// Numerics unchanged: fp16 2-term split, 3 products (t0t0 + 2^-12*(t0t1'+t1't0)),
// K-split x2 with atomicAdd into zeroed fp32. LDS layout byte-identical to R5
// (lane-linear both ways, 0 conflicts verified).

#define TN 2048

typedef float f32x4 __attribute__((ext_vector_type(4)));
typedef _Float16 f16;
typedef f16 f16x8 __attribute__((ext_vector_type(8)));
typedef f16 f16x4 __attribute__((ext_vector_type(4)));

#define MFMA16(a, b, c) __builtin_amdgcn_mfma_f32_16x16x32_f16(a, b, c, 0, 0, 0)

// async global->LDS, 16B per lane. lds base must be wave-uniform; HW adds lane*16.
__device__ __forceinline__ void glds16(const f16* g, f16* l) {
    __builtin_amdgcn_global_load_lds(
        (const __attribute__((address_space(1))) unsigned int*)g,
        (__attribute__((address_space(3))) unsigned int*)l, 16, 0, 0);
}

// ---------------- split kernels: a ~= t0 + t1'/4096 ----------------
__global__ void split2_kernel(const float* __restrict__ in,
                              f16* __restrict__ t0, f16* __restrict__ t1) {
    int i = (blockIdx.x * 256 + threadIdx.x) * 4;
    f32x4 f = *(const f32x4*)(in + i);
    f16x4 o0, o1;
#pragma unroll
    for (int e = 0; e < 4; ++e) {
        float a = f[e];
        f16 h0 = (f16)a;
        float r = (a - (float)h0) * 4096.f;
        o0[e] = h0; o1[e] = (f16)r;
    }
    *(f16x4*)(t0 + i) = o0; *(f16x4*)(t1 + i) = o1;
}

__global__ void split2t_kernel(const float* __restrict__ in,
                               f16* __restrict__ t0, f16* __restrict__ t1) {
    __shared__ f16 s0[64][68], s1[64][68];
    int bc = blockIdx.x * 64, br = blockIdx.y * 64;
    int tx = threadIdx.x & 15, ty = threadIdx.x >> 4;
#pragma unroll
    for (int rr = 0; rr < 64; rr += 16) {
        int r = rr + ty;
        f32x4 f = *(const f32x4*)(in + (size_t)(br + r) * TN + bc + tx * 4);
#pragma unroll
        for (int e = 0; e < 4; ++e) {
            float a = f[e];
            f16 h0 = (f16)a;
            float rr2 = (a - (float)h0) * 4096.f;
            s0[tx * 4 + e][r] = h0; s1[tx * 4 + e][r] = (f16)rr2;
        }
    }
    __syncthreads();
#pragma unroll
    for (int rr = 0; rr < 64; rr += 16) {
        int c = rr + ty;
        f16x4 o0, o1;
#pragma unroll
        for (int e = 0; e < 4; ++e) { o0[e] = s0[c][tx*4+e]; o1[e] = s1[c][tx*4+e]; }
        size_t off = (size_t)(bc + c) * TN + br + tx * 4;
        *(f16x4*)(t0 + off) = o0; *(f16x4*)(t1 + off) = o1;
    }
}

__global__ void cast1t_kernel(const float* __restrict__ in, f16* __restrict__ t0) {
    __shared__ f16 s0[64][68];
    int bc = blockIdx.x * 64, br = blockIdx.y * 64;
    int tx = threadIdx.x & 15, ty = threadIdx.x >> 4;
#pragma unroll
    for (int rr = 0; rr < 64; rr += 16) {
        int r = rr + ty;
        f32x4 f = *(const f32x4*)(in + (size_t)(br + r) * TN + bc + tx * 4);
#pragma unroll
        for (int e = 0; e < 4; ++e) s0[tx * 4 + e][r] = (f16)f[e];
    }
    __syncthreads();
#pragma unroll
    for (int rr = 0; rr < 64; rr += 16) {
        int c = rr + ty;
        f16x4 o0;
#pragma unroll
        for (int e = 0; e < 4; ++e) o0[e] = s0[c][tx*4+e];
        *(f16x4*)(t0 + (size_t)(bc + c) * TN + br + tx * 4) = o0;
    }
}

// ---------------- 3-product split GEMM, 128x128, K-split x2, glds double-buffered ----------------
// Per step: barrier (drains glds issued last step -> buf[p] ready); ds_read 16
// frags from buf[p]; issue 8 global_load_lds into buf[1-p] (completes under the
// MFMA region, drained by next barrier); 48 MFMA.
__global__ __launch_bounds__(256, 2) void gemm3_f16(
    const f16* __restrict__ a0p, const f16* __restrict__ a1p,
    const f16* __restrict__ b0p, const f16* __restrict__ b1p,
    float* __restrict__ C) {
    __shared__ f16 lds[2][32 * 512];  // 64 KB
    const int tid = threadIdx.x;
    const int wave = tid >> 6, lane = tid & 63;
    const int wr = (wave >> 1) * 64, wc = (wave & 1) * 64;
    const int quad = lane >> 4, l16 = lane & 15;
    const int bm = blockIdx.y * 128, bn = blockIdx.x * 128;
    const int kbase = blockIdx.z * 1024;

    const f16* sp[8];
#pragma unroll
    for (int t = 0; t < 8; ++t) {
        int s = wave * 8 + t;
        const f16* base; int gr;
        if (s < 16) { base = (s & 8) ? a1p : a0p; gr = bm + (s & 7) * 16 + l16; }
        else        { base = (s & 8) ? b1p : b0p; gr = bn + (s & 7) * 16 + l16; }
        sp[t] = base + (size_t)gr * TN + kbase + quad * 8;
    }
    const int seg = wave * 8;       // staging segment base (x512 f16; +lane*16B by HW)
    const int rof = lane * 8;       // read offset within segment

    f32x4 acc1[4][4], acc2[4][4];
#pragma unroll
    for (int i = 0; i < 4; ++i)
#pragma unroll
        for (int j = 0; j < 4; ++j) {
            acc1[i][j] = (f32x4){0.f, 0.f, 0.f, 0.f};
            acc2[i][j] = (f32x4){0.f, 0.f, 0.f, 0.f};
        }

    // prologue: issue step0 staging into buf0
#pragma unroll
    for (int t = 0; t < 8; ++t) { glds16(sp[t], &lds[0][(seg + t) * 512]); sp[t] += 32; }

    for (int step = 0; step < 32; ++step) {
        const int p = step & 1;
        __syncthreads();  // compiler drains vmcnt(0): buf[p] staged; prior reads of buf[1-p] done
        const f16* rdb = &lds[p][0] + rof;
        f16x8 b0f[4], b1f[4], a0f[4], a1f[4];
#pragma unroll
        for (int j = 0; j < 4; ++j) {
            b0f[j] = *(const f16x8*)(rdb + (16 + (wc >> 4) + j) * 512);
            b1f[j] = *(const f16x8*)(rdb + (24 + (wc >> 4) + j) * 512);
        }
#pragma unroll
        for (int i = 0; i < 4; ++i) {
            a0f[i] = *(const f16x8*)(rdb + ((wr >> 4) + i) * 512);
            a1f[i] = *(const f16x8*)(rdb + (8 + (wr >> 4) + i) * 512);
        }
        if (step < 31) {
            f16* dst = &lds[1 - p][0];
#pragma unroll
            for (int t = 0; t < 8; ++t) { glds16(sp[t], dst + (seg + t) * 512); sp[t] += 32; }
        }
#pragma unroll
        for (int i = 0; i < 4; ++i)
#pragma unroll
            for (int j = 0; j < 4; ++j) {
                acc1[i][j] = MFMA16(a0f[i], b0f[j], acc1[i][j]);
                acc2[i][j] = MFMA16(a0f[i], b1f[j], acc2[i][j]);
                acc2[i][j] = MFMA16(a1f[i], b0f[j], acc2[i][j]);
            }
    }
    const float sc = 1.f / 4096.f;
#pragma unroll
    for (int i = 0; i < 4; ++i)
#pragma unroll
        for (int j = 0; j < 4; ++j) {
            int row = bm + wr + i * 16 + quad * 4;
            int col = bn + wc + j * 16 + l16;
            float* p = C + (size_t)row * TN + col;
#pragma unroll
            for (int r = 0; r < 4; ++r)
                atomicAdd(p + (size_t)r * TN, acc1[i][j][r] + acc2[i][j][r] * sc);
        }
}

// ---------------- single-product GEMM, glds double-buffered ----------------
__global__ __launch_bounds__(256, 2) void gemm1_f16(
    const f16* __restrict__ A, const f16* __restrict__ Bt,
    float* __restrict__ C) {
    __shared__ f16 lds[2][16 * 512];  // 32 KB
    const int tid = threadIdx.x;
    const int wave = tid >> 6, lane = tid & 63;
    const int wr = (wave >> 1) * 64, wc = (wave & 1) * 64;
    const int quad = lane >> 4, l16 = lane & 15;
    const int bm = blockIdx.y * 128, bn = blockIdx.x * 128;
    const int kbase = blockIdx.z * 1024;

    const f16* sp[4];
#pragma unroll
    for (int t = 0; t < 4; ++t) {
        int s = wave * 4 + t;
        const f16* base; int gr;
        if (s < 8) { base = A;  gr = bm + s * 16 + l16; }
        else       { base = Bt; gr = bn + (s - 8) * 16 + l16; }
        sp[t] = base + (size_t)gr * TN + kbase + quad * 8;
    }
    const int seg = wave * 4;
    const int rof = lane * 8;

    f32x4 acc[4][4];
#pragma unroll
    for (int i = 0; i < 4; ++i)
#pragma unroll
        for (int j = 0; j < 4; ++j) acc[i][j] = (f32x4){0.f, 0.f, 0.f, 0.f};

    // prologue: issue step0 staging into buf0
#pragma unroll
    for (int t = 0; t < 4; ++t) { glds16(sp[t], &lds[0][(seg + t) * 512]); sp[t] += 32; }

    for (int step = 0; step < 32; ++step) {
        const int p = step & 1;
        __syncthreads();
        const f16* rdb = &lds[p][0] + rof;
        f16x8 bf[4], af[4];
#pragma unroll
        for (int j = 0; j < 4; ++j) bf[j] = *(const f16x8*)(rdb + (8 + (wc >> 4) + j) * 512);
#pragma unroll
        for (int i = 0; i < 4; ++i) af[i] = *(const f16x8*)(rdb + ((wr >> 4) + i) * 512);
        if (step < 31) {
            f16* dst = &lds[1 - p][0];
#pragma unroll
            for (int t = 0; t < 4; ++t) { glds16(sp[t], dst + (seg + t) * 512); sp[t] += 32; }
        }
#pragma unroll
        for (int i = 0; i < 4; ++i)
#pragma unroll
            for (int j = 0; j < 4; ++j) acc[i][j] = MFMA16(af[i], bf[j], acc[i][j]);
    }
#pragma unroll
    for (int i = 0; i < 4; ++i)
#pragma unroll
        for (int j = 0; j < 4; ++j) {
            int row = bm + wr + i * 16 + quad * 4;
            int col = bn + wc + j * 16 + l16;
            float* p = C + (size_t)row * TN + col;
#pragma unroll
            for (int r = 0; r < 4; ++r) atomicAdd(p + (size_t)r * TN, acc[i][j][r]);
        }
}

// ---------------- softmax (fp32 in, fp16 P out) ----------------
__global__ void softmax_kernel(const float* __restrict__ S, f16* __restrict__ P) {
    __shared__ float red[256];
    const int row = blockIdx.x, tid = threadIdx.x;
    const float* s = S + (size_t)row * TN;
    float m = -3.4e38f;
    for (int c = tid; c < TN; c += 256) m = fmaxf(m, s[c]);
    red[tid] = m; __syncthreads();
    for (int st = 128; st > 0; st >>= 1) { if (tid < st) red[tid] = fmaxf(red[tid], red[tid + st]); __syncthreads(); }
    m = red[0]; __syncthreads();
    float sum = 0.f;
    for (int c = tid; c < TN; c += 256) sum += expf(s[c] - m);
    red[tid] = sum; __syncthreads();
    for (int st = 128; st > 0; st >>= 1) { if (tid < st) red[tid] += red[tid + st]; __syncthreads(); }
    float inv = 1.f / red[0];
    f16* p = P + (size_t)row * TN;
    for (int c = tid; c < TN; c += 256) p[c] = (f16)(expf(s[c] - m) * inv);
}

extern "C" void kernel_launch(void* const* d_in, const int* in_sizes, int n_in,
                              void* d_out, int out_size, void* d_ws, size_t ws_size,
                              hipStream_t stream) {
    const float* x = (const float*)d_in[0];
    const float* q = (const float*)d_in[1];
    const float* k = (const float*)d_in[2];
    const float* v = (const float*)d_in[3];
    float* out = (float*)d_out;
    const size_t M = (size_t)TN * TN;

    float* W1 = (float*)d_ws;
    float* W2 = W1 + M;
    f16* pl = (f16*)(W2 + M);
    f16 *x0 = pl,         *x1 = pl + M;
    f16 *q0 = pl + 2 * M, *q1 = pl + 3 * M;
    f16 *k0 = pl + 4 * M, *k1 = pl + 5 * M;
    f16 *v0 = pl + 6 * M;
    f16 *a0 = q0, *a1 = q1;
    f16 *b0 = k0, *b1 = k1;
    f16 *p0 = x1, *c0 = x0;

    dim3 bs(256);
    dim3 gsplit(TN * TN / 4 / 256);
    dim3 gt(TN / 64, TN / 64);
    dim3 gg(TN / 128, TN / 128, 2);   // 512 blocks, 2/CU

    hipMemsetAsync(d_out, 0, M * 4, stream);
    hipLaunchKernelGGL(split2_kernel,  gsplit, bs, 0, stream, x, x0, x1);
    hipLaunchKernelGGL(split2t_kernel, gt,     bs, 0, stream, q, q0, q1);
    hipLaunchKernelGGL(gemm3_f16, gg, bs, 0, stream, x0, x1, q0, q1, out);
    hipMemsetAsync(W1, 0, M * 4, stream);
    hipLaunchKernelGGL(split2t_kernel, gt, bs, 0, stream, k, k0, k1);
    hipLaunchKernelGGL(gemm3_f16, gg, bs, 0, stream, x0, x1, k0, k1, W1);
    hipLaunchKernelGGL(split2_kernel,  gsplit, bs, 0, stream, out, a0, a1);
    hipLaunchKernelGGL(split2t_kernel, gt,     bs, 0, stream, W1, b0, b1);
    hipMemsetAsync(W2, 0, M * 4, stream);
    hipLaunchKernelGGL(gemm3_f16, gg, bs, 0, stream, a0, a1, b0, b1, W2);
    hipLaunchKernelGGL(softmax_kernel, dim3(TN), bs, 0, stream, W2, p0);
    hipLaunchKernelGGL(cast1t_kernel, gt, bs, 0, stream, v, v0);
    hipMemsetAsync(W1, 0, M * 4, stream);
    hipLaunchKernelGGL(gemm1_f16, gg, bs, 0, stream, x0, v0, W1);
    hipLaunchKernelGGL(cast1t_kernel, gt, bs, 0, stream, W1, c0);
    hipMemsetAsync(d_out, 0, M * 4, stream);
    hipLaunchKernelGGL(gemm1_f16, gg, bs, 0, stream, p0, c0, out);
}

// Round 2
// 423.248 us; speedup vs baseline: 1.2483x; 1.2483x over previous
//
#include <hip/hip_runtime.h>
#include <stdint.h>

// softmax((x@q)@(x@k)) @ (x@v), N=2048, fp32 in/out.
// R7: de-atomize. K-split z=0/z=1 write SEPARATE fp32 partial buffers (W1,W2)
// with plain stores -- no atomicAdd, no hipMemsetAsync anywhere. Consumers
// (split/cast/softmax/final) read both partials and add (they were already
// reading those bytes). Softmax is now single-pass: 8 f32/thread in registers,
// one read of each partial, one f16x8 write. Gemm inner loop reverted to the
// R5 reg-staged double-buffer (measured 89.4 us vs glds 92.4 us): prefetch a
// full step ahead into VGPRs, ONE barrier/step. Numerics: fp16 2-term split,
// 3 products (t0t0 + 2^-12*(t0t1'+t1't0)); deterministic W1+W2 sum.

#define TN 2048

typedef float f32x4 __attribute__((ext_vector_type(4)));
typedef _Float16 f16;
typedef f16 f16x8 __attribute__((ext_vector_type(8)));
typedef f16 f16x4 __attribute__((ext_vector_type(4)));
typedef unsigned int u32x4 __attribute__((ext_vector_type(4)));

#define MFMA16(a, b, c) __builtin_amdgcn_mfma_f32_16x16x32_f16(a, b, c, 0, 0, 0)

// ---------------- split kernels: a ~= t0 + t1'/4096 ----------------
__global__ void split2_kernel(const float* __restrict__ in,
                              f16* __restrict__ t0, f16* __restrict__ t1) {
    int i = (blockIdx.x * 256 + threadIdx.x) * 4;
    f32x4 f = *(const f32x4*)(in + i);
    f16x4 o0, o1;
#pragma unroll
    for (int e = 0; e < 4; ++e) {
        float a = f[e];
        f16 h0 = (f16)a;
        float r = (a - (float)h0) * 4096.f;
        o0[e] = h0; o1[e] = (f16)r;
    }
    *(f16x4*)(t0 + i) = o0; *(f16x4*)(t1 + i) = o1;
}

// split of (A+B), elementwise partial-sum fused
__global__ void split2_add_kernel(const float* __restrict__ inA,
                                  const float* __restrict__ inB,
                                  f16* __restrict__ t0, f16* __restrict__ t1) {
    int i = (blockIdx.x * 256 + threadIdx.x) * 4;
    f32x4 fa = *(const f32x4*)(inA + i);
    f32x4 fb = *(const f32x4*)(inB + i);
    f16x4 o0, o1;
#pragma unroll
    for (int e = 0; e < 4; ++e) {
        float a = fa[e] + fb[e];
        f16 h0 = (f16)a;
        float r = (a - (float)h0) * 4096.f;
        o0[e] = h0; o1[e] = (f16)r;
    }
    *(f16x4*)(t0 + i) = o0; *(f16x4*)(t1 + i) = o1;
}

__global__ void split2t_kernel(const float* __restrict__ in,
                               f16* __restrict__ t0, f16* __restrict__ t1) {
    __shared__ f16 s0[64][68], s1[64][68];
    int bc = blockIdx.x * 64, br = blockIdx.y * 64;
    int tx = threadIdx.x & 15, ty = threadIdx.x >> 4;
#pragma unroll
    for (int rr = 0; rr < 64; rr += 16) {
        int r = rr + ty;
        f32x4 f = *(const f32x4*)(in + (size_t)(br + r) * TN + bc + tx * 4);
#pragma unroll
        for (int e = 0; e < 4; ++e) {
            float a = f[e];
            f16 h0 = (f16)a;
            float rr2 = (a - (float)h0) * 4096.f;
            s0[tx * 4 + e][r] = h0; s1[tx * 4 + e][r] = (f16)rr2;
        }
    }
    __syncthreads();
#pragma unroll
    for (int rr = 0; rr < 64; rr += 16) {
        int c = rr + ty;
        f16x4 o0, o1;
#pragma unroll
        for (int e = 0; e < 4; ++e) { o0[e] = s0[c][tx*4+e]; o1[e] = s1[c][tx*4+e]; }
        size_t off = (size_t)(bc + c) * TN + br + tx * 4;
        *(f16x4*)(t0 + off) = o0; *(f16x4*)(t1 + off) = o1;
    }
}

// transposed split of (A+B)
__global__ void split2t_add_kernel(const float* __restrict__ inA,
                                   const float* __restrict__ inB,
                                   f16* __restrict__ t0, f16* __restrict__ t1) {
    __shared__ f16 s0[64][68], s1[64][68];
    int bc = blockIdx.x * 64, br = blockIdx.y * 64;
    int tx = threadIdx.x & 15, ty = threadIdx.x >> 4;
#pragma unroll
    for (int rr = 0; rr < 64; rr += 16) {
        int r = rr + ty;
        size_t off = (size_t)(br + r) * TN + bc + tx * 4;
        f32x4 fa = *(const f32x4*)(inA + off);
        f32x4 fb = *(const f32x4*)(inB + off);
#pragma unroll
        for (int e = 0; e < 4; ++e) {
            float a = fa[e] + fb[e];
            f16 h0 = (f16)a;
            float rr2 = (a - (float)h0) * 4096.f;
            s0[tx * 4 + e][r] = h0; s1[tx * 4 + e][r] = (f16)rr2;
        }
    }
    __syncthreads();
#pragma unroll
    for (int rr = 0; rr < 64; rr += 16) {
        int c = rr + ty;
        f16x4 o0, o1;
#pragma unroll
        for (int e = 0; e < 4; ++e) { o0[e] = s0[c][tx*4+e]; o1[e] = s1[c][tx*4+e]; }
        size_t off = (size_t)(bc + c) * TN + br + tx * 4;
        *(f16x4*)(t0 + off) = o0; *(f16x4*)(t1 + off) = o1;
    }
}

__global__ void cast1t_kernel(const float* __restrict__ in, f16* __restrict__ t0) {
    __shared__ f16 s0[64][68];
    int bc = blockIdx.x * 64, br = blockIdx.y * 64;
    int tx = threadIdx.x & 15, ty = threadIdx.x >> 4;
#pragma unroll
    for (int rr = 0; rr < 64; rr += 16) {
        int r = rr + ty;
        f32x4 f = *(const f32x4*)(in + (size_t)(br + r) * TN + bc + tx * 4);
#pragma unroll
        for (int e = 0; e < 4; ++e) s0[tx * 4 + e][r] = (f16)f[e];
    }
    __syncthreads();
#pragma unroll
    for (int rr = 0; rr < 64; rr += 16) {
        int c = rr + ty;
        f16x4 o0;
#pragma unroll
        for (int e = 0; e < 4; ++e) o0[e] = s0[c][tx*4+e];
        *(f16x4*)(t0 + (size_t)(bc + c) * TN + br + tx * 4) = o0;
    }
}

// transposed cast of (A+B)
__global__ void cast1t_add_kernel(const float* __restrict__ inA,
                                  const float* __restrict__ inB,
                                  f16* __restrict__ t0) {
    __shared__ f16 s0[64][68];
    int bc = blockIdx.x * 64, br = blockIdx.y * 64;
    int tx = threadIdx.x & 15, ty = threadIdx.x >> 4;
#pragma unroll
    for (int rr = 0; rr < 64; rr += 16) {
        int r = rr + ty;
        size_t off = (size_t)(br + r) * TN + bc + tx * 4;
        f32x4 fa = *(const f32x4*)(inA + off);
        f32x4 fb = *(const f32x4*)(inB + off);
#pragma unroll
        for (int e = 0; e < 4; ++e) s0[tx * 4 + e][r] = (f16)(fa[e] + fb[e]);
    }
    __syncthreads();
#pragma unroll
    for (int rr = 0; rr < 64; rr += 16) {
        int c = rr + ty;
        f16x4 o0;
#pragma unroll
        for (int e = 0; e < 4; ++e) o0[e] = s0[c][tx*4+e];
        *(f16x4*)(t0 + (size_t)(bc + c) * TN + br + tx * 4) = o0;
    }
}

// out = A + B
__global__ void final_add_kernel(const float* __restrict__ inA,
                                 const float* __restrict__ inB,
                                 float* __restrict__ out) {
    int i = (blockIdx.x * 256 + threadIdx.x) * 4;
    f32x4 fa = *(const f32x4*)(inA + i);
    f32x4 fb = *(const f32x4*)(inB + i);
    f32x4 o;
#pragma unroll
    for (int e = 0; e < 4; ++e) o[e] = fa[e] + fb[e];
    *(f32x4*)(out + i) = o;
}

// ---------------- 3-product split GEMM, 128x128, K-split x2, double-buffered ----------------
// R5 staging: prefetch into VGPRs a full step ahead; ONE barrier/step.
// z=0 writes C0, z=1 writes C1 (plain stores, no atomics).
__global__ __launch_bounds__(256, 2) void gemm3_f16(
    const f16* __restrict__ a0p, const f16* __restrict__ a1p,
    const f16* __restrict__ b0p, const f16* __restrict__ b1p,
    float* __restrict__ C0, float* __restrict__ C1) {
    __shared__ f16 lds[2][32 * 512];  // 64 KB
    const int tid = threadIdx.x;
    const int wave = tid >> 6, lane = tid & 63;
    const int wr = (wave >> 1) * 64, wc = (wave & 1) * 64;
    const int quad = lane >> 4, l16 = lane & 15;
    const int bm = blockIdx.y * 128, bn = blockIdx.x * 128;
    const int kbase = blockIdx.z * 1024;
    float* __restrict__ C = blockIdx.z ? C1 : C0;

    const f16* sp[8];
#pragma unroll
    for (int t = 0; t < 8; ++t) {
        int s = wave * 8 + t;
        const f16* base; int gr;
        if (s < 16) { base = (s & 8) ? a1p : a0p; gr = bm + (s & 7) * 16 + l16; }
        else        { base = (s & 8) ? b1p : b0p; gr = bn + (s & 7) * 16 + l16; }
        sp[t] = base + (size_t)gr * TN + kbase + quad * 8;
    }
    const int dof = wave * 8 * 512 + lane * 8;  // staging offset within buffer
    const int rof = lane * 8;                   // read offset within segment

    f32x4 acc1[4][4], acc2[4][4];
#pragma unroll
    for (int i = 0; i < 4; ++i)
#pragma unroll
        for (int j = 0; j < 4; ++j) {
            acc1[i][j] = (f32x4){0.f, 0.f, 0.f, 0.f};
            acc2[i][j] = (f32x4){0.f, 0.f, 0.f, 0.f};
        }

    u32x4 g[8];
    // prologue: step0 -> buf0; prefetch step1 into g
#pragma unroll
    for (int t = 0; t < 8; ++t) { g[t] = *(const u32x4*)sp[t]; sp[t] += 32; }
#pragma unroll
    for (int t = 0; t < 8; ++t) *(u32x4*)(&lds[0][0] + dof + t * 512) = g[t];
#pragma unroll
    for (int t = 0; t < 8; ++t) { g[t] = *(const u32x4*)sp[t]; sp[t] += 32; }

    for (int step = 0; step < 32; ++step) {
        const int p = step & 1;
        __syncthreads();
        const f16* rdb = &lds[p][0] + rof;
        f16x8 b0f[4], b1f[4], a0f[4], a1f[4];
#pragma unroll
        for (int j = 0; j < 4; ++j) {
            b0f[j] = *(const f16x8*)(rdb + (16 + (wc >> 4) + j) * 512);
            b1f[j] = *(const f16x8*)(rdb + (24 + (wc >> 4) + j) * 512);
        }
#pragma unroll
        for (int i = 0; i < 4; ++i) {
            a0f[i] = *(const f16x8*)(rdb + ((wr >> 4) + i) * 512);
            a1f[i] = *(const f16x8*)(rdb + (8 + (wr >> 4) + i) * 512);
        }
        if (step < 31) {
            f16* dst = &lds[1 - p][0] + dof;
#pragma unroll
            for (int t = 0; t < 8; ++t) *(u32x4*)(dst + t * 512) = g[t];
        }
        if (step < 30) {
#pragma unroll
            for (int t = 0; t < 8; ++t) { g[t] = *(const u32x4*)sp[t]; sp[t] += 32; }
        }
#pragma unroll
        for (int i = 0; i < 4; ++i)
#pragma unroll
            for (int j = 0; j < 4; ++j) {
                acc1[i][j] = MFMA16(a0f[i], b0f[j], acc1[i][j]);
                acc2[i][j] = MFMA16(a0f[i], b1f[j], acc2[i][j]);
                acc2[i][j] = MFMA16(a1f[i], b0f[j], acc2[i][j]);
            }
    }
    const float sc = 1.f / 4096.f;
#pragma unroll
    for (int i = 0; i < 4; ++i)
#pragma unroll
        for (int j = 0; j < 4; ++j) {
            int row = bm + wr + i * 16 + quad * 4;
            int col = bn + wc + j * 16 + l16;
            float* p = C + (size_t)row * TN + col;
#pragma unroll
            for (int r = 0; r < 4; ++r)
                p[(size_t)r * TN] = acc1[i][j][r] + acc2[i][j][r] * sc;
        }
}

// ---------------- single-product GEMM, double-buffered ----------------
__global__ __launch_bounds__(256, 2) void gemm1_f16(
    const f16* __restrict__ A, const f16* __restrict__ Bt,
    float* __restrict__ C0, float* __restrict__ C1) {
    __shared__ f16 lds[2][16 * 512];  // 32 KB
    const int tid = threadIdx.x;
    const int wave = tid >> 6, lane = tid & 63;
    const int wr = (wave >> 1) * 64, wc = (wave & 1) * 64;
    const int quad = lane >> 4, l16 = lane & 15;
    const int bm = blockIdx.y * 128, bn = blockIdx.x * 128;
    const int kbase = blockIdx.z * 1024;
    float* __restrict__ C = blockIdx.z ? C1 : C0;

    const f16* sp[4];
#pragma unroll
    for (int t = 0; t < 4; ++t) {
        int s = wave * 4 + t;
        const f16* base; int gr;
        if (s < 8) { base = A;  gr = bm + s * 16 + l16; }
        else       { base = Bt; gr = bn + (s - 8) * 16 + l16; }
        sp[t] = base + (size_t)gr * TN + kbase + quad * 8;
    }
    const int dof = wave * 4 * 512 + lane * 8;
    const int rof = lane * 8;

    f32x4 acc[4][4];
#pragma unroll
    for (int i = 0; i < 4; ++i)
#pragma unroll
        for (int j = 0; j < 4; ++j) acc[i][j] = (f32x4){0.f, 0.f, 0.f, 0.f};

    u32x4 g[4];
#pragma unroll
    for (int t = 0; t < 4; ++t) { g[t] = *(const u32x4*)sp[t]; sp[t] += 32; }
#pragma unroll
    for (int t = 0; t < 4; ++t) *(u32x4*)(&lds[0][0] + dof + t * 512) = g[t];
#pragma unroll
    for (int t = 0; t < 4; ++t) { g[t] = *(const u32x4*)sp[t]; sp[t] += 32; }

    for (int step = 0; step < 32; ++step) {
        const int p = step & 1;
        __syncthreads();
        const f16* rdb = &lds[p][0] + rof;
        f16x8 bf[4], af[4];
#pragma unroll
        for (int j = 0; j < 4; ++j) bf[j] = *(const f16x8*)(rdb + (8 + (wc >> 4) + j) * 512);
#pragma unroll
        for (int i = 0; i < 4; ++i) af[i] = *(const f16x8*)(rdb + ((wr >> 4) + i) * 512);
        if (step < 31) {
            f16* dst = &lds[1 - p][0] + dof;
#pragma unroll
            for (int t = 0; t < 4; ++t) *(u32x4*)(dst + t * 512) = g[t];
        }
        if (step < 30) {
#pragma unroll
            for (int t = 0; t < 4; ++t) { g[t] = *(const u32x4*)sp[t]; sp[t] += 32; }
        }
#pragma unroll
        for (int i = 0; i < 4; ++i)
#pragma unroll
            for (int j = 0; j < 4; ++j) acc[i][j] = MFMA16(af[i], bf[j], acc[i][j]);
    }
#pragma unroll
    for (int i = 0; i < 4; ++i)
#pragma unroll
        for (int j = 0; j < 4; ++j) {
            int row = bm + wr + i * 16 + quad * 4;
            int col = bn + wc + j * 16 + l16;
            float* p = C + (size_t)row * TN + col;
#pragma unroll
            for (int r = 0; r < 4; ++r) p[(size_t)r * TN] = acc[i][j][r];
        }
}

// ---------------- softmax of (S0+S1), single-pass (fp32 in, fp16 P out) ----------------
__global__ void softmax_add_kernel(const float* __restrict__ S0,
                                   const float* __restrict__ S1,
                                   f16* __restrict__ P) {
    __shared__ float red[256];
    const int row = blockIdx.x, tid = threadIdx.x;
    const size_t base = (size_t)row * TN + tid * 8;
    f32x4 a0 = *(const f32x4*)(S0 + base);
    f32x4 a1 = *(const f32x4*)(S0 + base + 4);
    f32x4 b0 = *(const f32x4*)(S1 + base);
    f32x4 b1 = *(const f32x4*)(S1 + base + 4);
    float vals[8];
#pragma unroll
    for (int e = 0; e < 4; ++e) { vals[e] = a0[e] + b0[e]; vals[4 + e] = a1[e] + b1[e]; }
    float m = vals[0];
#pragma unroll
    for (int e = 1; e < 8; ++e) m = fmaxf(m, vals[e]);
    red[tid] = m; __syncthreads();
    for (int st = 128; st > 0; st >>= 1) { if (tid < st) red[tid] = fmaxf(red[tid], red[tid + st]); __syncthreads(); }
    m = red[0]; __syncthreads();
    float sum = 0.f;
#pragma unroll
    for (int e = 0; e < 8; ++e) { vals[e] = expf(vals[e] - m); sum += vals[e]; }
    red[tid] = sum; __syncthreads();
    for (int st = 128; st > 0; st >>= 1) { if (tid < st) red[tid] += red[tid + st]; __syncthreads(); }
    float inv = 1.f / red[0];
    f16x8 o;
#pragma unroll
    for (int e = 0; e < 8; ++e) o[e] = (f16)(vals[e] * inv);
    *(f16x8*)(P + base) = o;
}

extern "C" void kernel_launch(void* const* d_in, const int* in_sizes, int n_in,
                              void* d_out, int out_size, void* d_ws, size_t ws_size,
                              hipStream_t stream) {
    const float* x = (const float*)d_in[0];
    const float* q = (const float*)d_in[1];
    const float* k = (const float*)d_in[2];
    const float* v = (const float*)d_in[3];
    float* out = (float*)d_out;
    const size_t M = (size_t)TN * TN;

    float* W1 = (float*)d_ws;
    float* W2 = W1 + M;
    f16* pl = (f16*)(W2 + M);
    f16 *x0 = pl,         *x1 = pl + M;
    f16 *q0 = pl + 2 * M, *q1 = pl + 3 * M;
    f16 *k0 = pl + 4 * M, *k1 = pl + 5 * M;
    f16 *v0 = pl + 6 * M;
    f16 *a0 = q0, *a1 = q1;   // xq split reuses q planes
    f16 *b0 = k0, *b1 = k1;   // xk split reuses k planes
    f16 *p0 = x1, *c0 = x0;   // P reuses x1 (dead after gemm3#2), C reuses x0 (dead after gemm1#1)

    dim3 bs(256);
    dim3 gelem(TN * TN / 4 / 256);
    dim3 gt(TN / 64, TN / 64);
    dim3 gg(TN / 128, TN / 128, 2);   // 512 blocks, 2/CU

    hipLaunchKernelGGL(split2_kernel,  gelem, bs, 0, stream, x, x0, x1);
    hipLaunchKernelGGL(cast1t_kernel,  gt,    bs, 0, stream, v, v0);
    hipLaunchKernelGGL(split2t_kernel, gt,    bs, 0, stream, q, q0, q1);
    hipLaunchKernelGGL(gemm3_f16, gg, bs, 0, stream, x0, x1, q0, q1, W1, W2);
    hipLaunchKernelGGL(split2_add_kernel, gelem, bs, 0, stream, W1, W2, a0, a1);
    hipLaunchKernelGGL(split2t_kernel, gt, bs, 0, stream, k, k0, k1);
    hipLaunchKernelGGL(gemm3_f16, gg, bs, 0, stream, x0, x1, k0, k1, W1, W2);
    hipLaunchKernelGGL(split2t_add_kernel, gt, bs, 0, stream, W1, W2, b0, b1);
    hipLaunchKernelGGL(gemm3_f16, gg, bs, 0, stream, a0, a1, b0, b1, W1, W2);
    hipLaunchKernelGGL(softmax_add_kernel, dim3(TN), bs, 0, stream, W1, W2, p0);
    hipLaunchKernelGGL(gemm1_f16, gg, bs, 0, stream, x0, v0, W1, W2);
    hipLaunchKernelGGL(cast1t_add_kernel, gt, bs, 0, stream, W1, W2, c0);
    hipLaunchKernelGGL(gemm1_f16, gg, bs, 0, stream, p0, c0, W1, W2);
    hipLaunchKernelGGL(final_add_kernel, gelem, bs, 0, stream, W1, W2, out);
}

// Round 3
// 390.780 us; speedup vs baseline: 1.3520x; 1.0831x over previous
//
#include <hip/hip_runtime.h>
#include <stdint.h>

// softmax((x@q)@(x@k)) @ (x@v), N=2048, fp32 in/out.
// R8: counted-vmcnt phase pipeline (T3+T4+T5). gemm3: 128x256 tile, 8 waves,
// TRIPLE-buffered LDS (3x48KB), global_load_lds staging issued 2 steps ahead,
// 3 phases/step (one MFMA cluster per product), raw s_barrier (NO vmcnt(0)
// drain in loop), s_waitcnt vmcnt(6) counted once/step, setprio around MFMA.
// Single accumulator: residual planes stored UNSCALED (a ~= t0 + t1, t1 tiny)
// so all 3 products accumulate into one acc (64 AGPR) -- no epilogue scale.
// gemm1: same 3-buffer machinery, 128^2 tile, 4 waves, 2 blocks/CU.
// Safety: all ds_reads of a buffer retire (via MFMA uses) before the barrier
// releasing its overwriting glds batch; batch completion gated by vmcnt+barrier.
// K-split z=0/1 -> W1/W2 plain stores; consumers add (R7 scheme unchanged).

#define TN 2048

typedef float f32x4 __attribute__((ext_vector_type(4)));
typedef _Float16 f16;
typedef f16 f16x8 __attribute__((ext_vector_type(8)));
typedef f16 f16x4 __attribute__((ext_vector_type(4)));

#define MFMA16(a, b, c) __builtin_amdgcn_mfma_f32_16x16x32_f16(a, b, c, 0, 0, 0)
#define SBAR() asm volatile("s_barrier" ::: "memory")
#define VMCNT(n) asm volatile("s_waitcnt vmcnt(" #n ")" ::: "memory")

// async global->LDS, 16B/lane. lds base wave-uniform; HW adds lane*16.
__device__ __forceinline__ void glds16(const f16* g, f16* l) {
    __builtin_amdgcn_global_load_lds(
        (const __attribute__((address_space(1))) unsigned int*)g,
        (__attribute__((address_space(3))) unsigned int*)l, 16, 0, 0);
}

// ---------------- split kernels: a ~= t0 + t1 (residual UNSCALED) ----------------
__global__ void split2_kernel(const float* __restrict__ in,
                              f16* __restrict__ t0, f16* __restrict__ t1) {
    int i = (blockIdx.x * 256 + threadIdx.x) * 4;
    f32x4 f = *(const f32x4*)(in + i);
    f16x4 o0, o1;
#pragma unroll
    for (int e = 0; e < 4; ++e) {
        float a = f[e];
        f16 h0 = (f16)a;
        o0[e] = h0; o1[e] = (f16)(a - (float)h0);
    }
    *(f16x4*)(t0 + i) = o0; *(f16x4*)(t1 + i) = o1;
}

__global__ void split2_add_kernel(const float* __restrict__ inA,
                                  const float* __restrict__ inB,
                                  f16* __restrict__ t0, f16* __restrict__ t1) {
    int i = (blockIdx.x * 256 + threadIdx.x) * 4;
    f32x4 fa = *(const f32x4*)(inA + i);
    f32x4 fb = *(const f32x4*)(inB + i);
    f16x4 o0, o1;
#pragma unroll
    for (int e = 0; e < 4; ++e) {
        float a = fa[e] + fb[e];
        f16 h0 = (f16)a;
        o0[e] = h0; o1[e] = (f16)(a - (float)h0);
    }
    *(f16x4*)(t0 + i) = o0; *(f16x4*)(t1 + i) = o1;
}

__global__ void split2t_kernel(const float* __restrict__ in,
                               f16* __restrict__ t0, f16* __restrict__ t1) {
    __shared__ f16 s0[64][68], s1[64][68];
    int bc = blockIdx.x * 64, br = blockIdx.y * 64;
    int tx = threadIdx.x & 15, ty = threadIdx.x >> 4;
#pragma unroll
    for (int rr = 0; rr < 64; rr += 16) {
        int r = rr + ty;
        f32x4 f = *(const f32x4*)(in + (size_t)(br + r) * TN + bc + tx * 4);
#pragma unroll
        for (int e = 0; e < 4; ++e) {
            float a = f[e];
            f16 h0 = (f16)a;
            s0[tx * 4 + e][r] = h0; s1[tx * 4 + e][r] = (f16)(a - (float)h0);
        }
    }
    __syncthreads();
#pragma unroll
    for (int rr = 0; rr < 64; rr += 16) {
        int c = rr + ty;
        f16x4 o0, o1;
#pragma unroll
        for (int e = 0; e < 4; ++e) { o0[e] = s0[c][tx*4+e]; o1[e] = s1[c][tx*4+e]; }
        size_t off = (size_t)(bc + c) * TN + br + tx * 4;
        *(f16x4*)(t0 + off) = o0; *(f16x4*)(t1 + off) = o1;
    }
}

__global__ void split2t_add_kernel(const float* __restrict__ inA,
                                   const float* __restrict__ inB,
                                   f16* __restrict__ t0, f16* __restrict__ t1) {
    __shared__ f16 s0[64][68], s1[64][68];
    int bc = blockIdx.x * 64, br = blockIdx.y * 64;
    int tx = threadIdx.x & 15, ty = threadIdx.x >> 4;
#pragma unroll
    for (int rr = 0; rr < 64; rr += 16) {
        int r = rr + ty;
        size_t off = (size_t)(br + r) * TN + bc + tx * 4;
        f32x4 fa = *(const f32x4*)(inA + off);
        f32x4 fb = *(const f32x4*)(inB + off);
#pragma unroll
        for (int e = 0; e < 4; ++e) {
            float a = fa[e] + fb[e];
            f16 h0 = (f16)a;
            s0[tx * 4 + e][r] = h0; s1[tx * 4 + e][r] = (f16)(a - (float)h0);
        }
    }
    __syncthreads();
#pragma unroll
    for (int rr = 0; rr < 64; rr += 16) {
        int c = rr + ty;
        f16x4 o0, o1;
#pragma unroll
        for (int e = 0; e < 4; ++e) { o0[e] = s0[c][tx*4+e]; o1[e] = s1[c][tx*4+e]; }
        size_t off = (size_t)(bc + c) * TN + br + tx * 4;
        *(f16x4*)(t0 + off) = o0; *(f16x4*)(t1 + off) = o1;
    }
}

__global__ void cast1t_kernel(const float* __restrict__ in, f16* __restrict__ t0) {
    __shared__ f16 s0[64][68];
    int bc = blockIdx.x * 64, br = blockIdx.y * 64;
    int tx = threadIdx.x & 15, ty = threadIdx.x >> 4;
#pragma unroll
    for (int rr = 0; rr < 64; rr += 16) {
        int r = rr + ty;
        f32x4 f = *(const f32x4*)(in + (size_t)(br + r) * TN + bc + tx * 4);
#pragma unroll
        for (int e = 0; e < 4; ++e) s0[tx * 4 + e][r] = (f16)f[e];
    }
    __syncthreads();
#pragma unroll
    for (int rr = 0; rr < 64; rr += 16) {
        int c = rr + ty;
        f16x4 o0;
#pragma unroll
        for (int e = 0; e < 4; ++e) o0[e] = s0[c][tx*4+e];
        *(f16x4*)(t0 + (size_t)(bc + c) * TN + br + tx * 4) = o0;
    }
}

__global__ void cast1t_add_kernel(const float* __restrict__ inA,
                                  const float* __restrict__ inB,
                                  f16* __restrict__ t0) {
    __shared__ f16 s0[64][68];
    int bc = blockIdx.x * 64, br = blockIdx.y * 64;
    int tx = threadIdx.x & 15, ty = threadIdx.x >> 4;
#pragma unroll
    for (int rr = 0; rr < 64; rr += 16) {
        int r = rr + ty;
        size_t off = (size_t)(br + r) * TN + bc + tx * 4;
        f32x4 fa = *(const f32x4*)(inA + off);
        f32x4 fb = *(const f32x4*)(inB + off);
#pragma unroll
        for (int e = 0; e < 4; ++e) s0[tx * 4 + e][r] = (f16)(fa[e] + fb[e]);
    }
    __syncthreads();
#pragma unroll
    for (int rr = 0; rr < 64; rr += 16) {
        int c = rr + ty;
        f16x4 o0;
#pragma unroll
        for (int e = 0; e < 4; ++e) o0[e] = s0[c][tx*4+e];
        *(f16x4*)(t0 + (size_t)(bc + c) * TN + br + tx * 4) = o0;
    }
}

__global__ void final_add_kernel(const float* __restrict__ inA,
                                 const float* __restrict__ inB,
                                 float* __restrict__ out) {
    int i = (blockIdx.x * 256 + threadIdx.x) * 4;
    f32x4 fa = *(const f32x4*)(inA + i);
    f32x4 fb = *(const f32x4*)(inB + i);
    f32x4 o;
#pragma unroll
    for (int e = 0; e < 4; ++e) o[e] = fa[e] + fb[e];
    *(f32x4*)(out + i) = o;
}

// ---------------- 3-product split GEMM, 128x256 tile, 8 waves, 3-buf pipeline ----------------
// Per step (K=32): [A: read b1f(cur); glds t0..2->pre; bar; 16 MFMA a0*b0]
// [B: read a1f(cur); glds t3..5->pre; bar; 16 MFMA a0*b1]
// [C: 16 MFMA a1*b0; vmcnt(6); bar; read a0f,b0f(nxt)] rotate.
__global__ __launch_bounds__(512, 2) void gemm3_f16(
    const f16* __restrict__ a0p, const f16* __restrict__ a1p,
    const f16* __restrict__ b0p, const f16* __restrict__ b1p,
    float* __restrict__ C0, float* __restrict__ C1) {
    __shared__ f16 lds[3][48 * 512];  // 144 KB
    const int tid = threadIdx.x;
    const int wave = tid >> 6, lane = tid & 63;
    const int wrow = wave >> 2, wcol = wave & 3;
    const int quad = lane >> 4, l16 = lane & 15;
    const int bm = blockIdx.y * 128, bn = blockIdx.x * 256;
    const int kbase = blockIdx.z * 1024;
    float* __restrict__ C = blockIdx.z ? C1 : C0;

    const int ws = wave * 6;
    const f16* sp[6];
#pragma unroll
    for (int t = 0; t < 6; ++t) {
        int s = ws + t;
        const f16* base; int gr;
        if (s < 8)       { base = a0p; gr = bm + s * 16 + l16; }
        else if (s < 16) { base = a1p; gr = bm + (s - 8) * 16 + l16; }
        else if (s < 32) { base = b0p; gr = bn + (s - 16) * 16 + l16; }
        else             { base = b1p; gr = bn + (s - 32) * 16 + l16; }
        sp[t] = base + (size_t)gr * TN + kbase + quad * 8;
    }
    const int rof = lane * 8;
    const int sa0 = wrow * 4, sa1 = 8 + wrow * 4;
    const int sb0 = 16 + wcol * 4, sb1 = 32 + wcol * 4;

    f32x4 acc[4][4];
#pragma unroll
    for (int i = 0; i < 4; ++i)
#pragma unroll
        for (int j = 0; j < 4; ++j) acc[i][j] = (f32x4){0.f, 0.f, 0.f, 0.f};

    // prologue: batches for step0 -> buf0, step1 -> buf1
#pragma unroll
    for (int t = 0; t < 6; ++t) { glds16(sp[t], &lds[0][(ws + t) * 512]); sp[t] += 32; }
#pragma unroll
    for (int t = 0; t < 6; ++t) { glds16(sp[t], &lds[1][(ws + t) * 512]); sp[t] += 32; }
    f16* cur = &lds[0][0]; f16* nxt = &lds[1][0]; f16* pre = &lds[2][0];
    VMCNT(6); SBAR();

    f16x8 a0f[4], a1f[4], b0f[4], b1f[4];
#pragma unroll
    for (int i = 0; i < 4; ++i) a0f[i] = *(const f16x8*)(cur + (sa0 + i) * 512 + rof);
#pragma unroll
    for (int j = 0; j < 4; ++j) b0f[j] = *(const f16x8*)(cur + (sb0 + j) * 512 + rof);

    for (int step = 0; step < 32; ++step) {
        // ---- phase A ----
#pragma unroll
        for (int j = 0; j < 4; ++j) b1f[j] = *(const f16x8*)(cur + (sb1 + j) * 512 + rof);
        if (step < 30) {
#pragma unroll
            for (int t = 0; t < 3; ++t) { glds16(sp[t], pre + (ws + t) * 512); sp[t] += 32; }
        }
        SBAR();
        __builtin_amdgcn_s_setprio(1);
#pragma unroll
        for (int i = 0; i < 4; ++i)
#pragma unroll
            for (int j = 0; j < 4; ++j) acc[i][j] = MFMA16(a0f[i], b0f[j], acc[i][j]);
        __builtin_amdgcn_s_setprio(0);
        // ---- phase B ----
#pragma unroll
        for (int i = 0; i < 4; ++i) a1f[i] = *(const f16x8*)(cur + (sa1 + i) * 512 + rof);
        if (step < 30) {
#pragma unroll
            for (int t = 3; t < 6; ++t) { glds16(sp[t], pre + (ws + t) * 512); sp[t] += 32; }
        }
        SBAR();
        __builtin_amdgcn_s_setprio(1);
#pragma unroll
        for (int i = 0; i < 4; ++i)
#pragma unroll
            for (int j = 0; j < 4; ++j) acc[i][j] = MFMA16(a0f[i], b1f[j], acc[i][j]);
        __builtin_amdgcn_s_setprio(0);
        // ---- phase C ----
        __builtin_amdgcn_s_setprio(1);
#pragma unroll
        for (int i = 0; i < 4; ++i)
#pragma unroll
            for (int j = 0; j < 4; ++j) acc[i][j] = MFMA16(a1f[i], b0f[j], acc[i][j]);
        __builtin_amdgcn_s_setprio(0);
        if (step < 31) {
            if (step < 30) { VMCNT(6); } else { VMCNT(0); }
            SBAR();
#pragma unroll
            for (int i = 0; i < 4; ++i) a0f[i] = *(const f16x8*)(nxt + (sa0 + i) * 512 + rof);
#pragma unroll
            for (int j = 0; j < 4; ++j) b0f[j] = *(const f16x8*)(nxt + (sb0 + j) * 512 + rof);
        }
        f16* tmp = cur; cur = nxt; nxt = pre; pre = tmp;
    }
#pragma unroll
    for (int i = 0; i < 4; ++i)
#pragma unroll
        for (int j = 0; j < 4; ++j) {
            int row = bm + wrow * 64 + i * 16 + quad * 4;
            int col = bn + wcol * 64 + j * 16 + l16;
            float* p = C + (size_t)row * TN + col;
#pragma unroll
            for (int r = 0; r < 4; ++r) p[(size_t)r * TN] = acc[i][j][r];
        }
}

// ---------------- single-product GEMM, 128x128, 4 waves, 3-buf pipeline ----------------
__global__ __launch_bounds__(256, 2) void gemm1_f16(
    const f16* __restrict__ A, const f16* __restrict__ Bt,
    float* __restrict__ C0, float* __restrict__ C1) {
    __shared__ f16 lds[3][16 * 512];  // 48 KB
    const int tid = threadIdx.x;
    const int wave = tid >> 6, lane = tid & 63;
    const int wr = (wave >> 1) * 64, wc = (wave & 1) * 64;
    const int quad = lane >> 4, l16 = lane & 15;
    const int bm = blockIdx.y * 128, bn = blockIdx.x * 128;
    const int kbase = blockIdx.z * 1024;
    float* __restrict__ C = blockIdx.z ? C1 : C0;

    const int ws = wave * 4;
    const f16* sp[4];
#pragma unroll
    for (int t = 0; t < 4; ++t) {
        int s = ws + t;
        const f16* base; int gr;
        if (s < 8) { base = A;  gr = bm + s * 16 + l16; }
        else       { base = Bt; gr = bn + (s - 8) * 16 + l16; }
        sp[t] = base + (size_t)gr * TN + kbase + quad * 8;
    }
    const int rof = lane * 8;
    const int sa = (wr >> 4), sb = 8 + (wc >> 4);

    f32x4 acc[4][4];
#pragma unroll
    for (int i = 0; i < 4; ++i)
#pragma unroll
        for (int j = 0; j < 4; ++j) acc[i][j] = (f32x4){0.f, 0.f, 0.f, 0.f};

#pragma unroll
    for (int t = 0; t < 4; ++t) { glds16(sp[t], &lds[0][(ws + t) * 512]); sp[t] += 32; }
#pragma unroll
    for (int t = 0; t < 4; ++t) { glds16(sp[t], &lds[1][(ws + t) * 512]); sp[t] += 32; }
    f16* cur = &lds[0][0]; f16* nxt = &lds[1][0]; f16* pre = &lds[2][0];
    VMCNT(4); SBAR();

    f16x8 af[4], bf[4];
#pragma unroll
    for (int i = 0; i < 4; ++i) af[i] = *(const f16x8*)(cur + (sa + i) * 512 + rof);
#pragma unroll
    for (int j = 0; j < 4; ++j) bf[j] = *(const f16x8*)(cur + (sb + j) * 512 + rof);

    for (int step = 0; step < 32; ++step) {
        if (step < 30) {
#pragma unroll
            for (int t = 0; t < 4; ++t) { glds16(sp[t], pre + (ws + t) * 512); sp[t] += 32; }
        }
        SBAR();
        __builtin_amdgcn_s_setprio(1);
#pragma unroll
        for (int i = 0; i < 4; ++i)
#pragma unroll
            for (int j = 0; j < 4; ++j) acc[i][j] = MFMA16(af[i], bf[j], acc[i][j]);
        __builtin_amdgcn_s_setprio(0);
        if (step < 31) {
            if (step < 30) { VMCNT(4); } else { VMCNT(0); }
            SBAR();
#pragma unroll
            for (int i = 0; i < 4; ++i) af[i] = *(const f16x8*)(nxt + (sa + i) * 512 + rof);
#pragma unroll
            for (int j = 0; j < 4; ++j) bf[j] = *(const f16x8*)(nxt + (sb + j) * 512 + rof);
        }
        f16* tmp = cur; cur = nxt; nxt = pre; pre = tmp;
    }
#pragma unroll
    for (int i = 0; i < 4; ++i)
#pragma unroll
        for (int j = 0; j < 4; ++j) {
            int row = bm + wr + i * 16 + quad * 4;
            int col = bn + wc + j * 16 + l16;
            float* p = C + (size_t)row * TN + col;
#pragma unroll
            for (int r = 0; r < 4; ++r) p[(size_t)r * TN] = acc[i][j][r];
        }
}

// ---------------- softmax of (S0+S1), single-pass (fp32 in, fp16 P out) ----------------
__global__ void softmax_add_kernel(const float* __restrict__ S0,
                                   const float* __restrict__ S1,
                                   f16* __restrict__ P) {
    __shared__ float red[256];
    const int row = blockIdx.x, tid = threadIdx.x;
    const size_t base = (size_t)row * TN + tid * 8;
    f32x4 a0 = *(const f32x4*)(S0 + base);
    f32x4 a1 = *(const f32x4*)(S0 + base + 4);
    f32x4 b0 = *(const f32x4*)(S1 + base);
    f32x4 b1 = *(const f32x4*)(S1 + base + 4);
    float vals[8];
#pragma unroll
    for (int e = 0; e < 4; ++e) { vals[e] = a0[e] + b0[e]; vals[4 + e] = a1[e] + b1[e]; }
    float m = vals[0];
#pragma unroll
    for (int e = 1; e < 8; ++e) m = fmaxf(m, vals[e]);
    red[tid] = m; __syncthreads();
    for (int st = 128; st > 0; st >>= 1) { if (tid < st) red[tid] = fmaxf(red[tid], red[tid + st]); __syncthreads(); }
    m = red[0]; __syncthreads();
    float sum = 0.f;
#pragma unroll
    for (int e = 0; e < 8; ++e) { vals[e] = expf(vals[e] - m); sum += vals[e]; }
    red[tid] = sum; __syncthreads();
    for (int st = 128; st > 0; st >>= 1) { if (tid < st) red[tid] += red[tid + st]; __syncthreads(); }
    float inv = 1.f / red[0];
    f16x8 o;
#pragma unroll
    for (int e = 0; e < 8; ++e) o[e] = (f16)(vals[e] * inv);
    *(f16x8*)(P + base) = o;
}

extern "C" void kernel_launch(void* const* d_in, const int* in_sizes, int n_in,
                              void* d_out, int out_size, void* d_ws, size_t ws_size,
                              hipStream_t stream) {
    const float* x = (const float*)d_in[0];
    const float* q = (const float*)d_in[1];
    const float* k = (const float*)d_in[2];
    const float* v = (const float*)d_in[3];
    float* out = (float*)d_out;
    const size_t M = (size_t)TN * TN;

    float* W1 = (float*)d_ws;
    float* W2 = W1 + M;
    f16* pl = (f16*)(W2 + M);
    f16 *x0 = pl,         *x1 = pl + M;
    f16 *q0 = pl + 2 * M, *q1 = pl + 3 * M;
    f16 *k0 = pl + 4 * M, *k1 = pl + 5 * M;
    f16 *v0 = pl + 6 * M;
    f16 *a0 = q0, *a1 = q1;   // xq split reuses q planes
    f16 *b0 = k0, *b1 = k1;   // xk split reuses k planes
    f16 *p0 = x1, *c0 = x0;   // P reuses x1, C reuses x0

    dim3 bs(256), bs3(512);
    dim3 gelem(TN * TN / 4 / 256);
    dim3 gt(TN / 64, TN / 64);
    dim3 gg3(TN / 256, TN / 128, 2);   // 256 blocks, 1/CU
    dim3 gg1(TN / 128, TN / 128, 2);   // 512 blocks, 2/CU

    hipLaunchKernelGGL(split2_kernel,  gelem, bs, 0, stream, x, x0, x1);
    hipLaunchKernelGGL(cast1t_kernel,  gt,    bs, 0, stream, v, v0);
    hipLaunchKernelGGL(split2t_kernel, gt,    bs, 0, stream, q, q0, q1);
    hipLaunchKernelGGL(gemm3_f16, gg3, bs3, 0, stream, x0, x1, q0, q1, W1, W2);
    hipLaunchKernelGGL(split2_add_kernel, gelem, bs, 0, stream, W1, W2, a0, a1);
    hipLaunchKernelGGL(split2t_kernel, gt, bs, 0, stream, k, k0, k1);
    hipLaunchKernelGGL(gemm3_f16, gg3, bs3, 0, stream, x0, x1, k0, k1, W1, W2);
    hipLaunchKernelGGL(split2t_add_kernel, gt, bs, 0, stream, W1, W2, b0, b1);
    hipLaunchKernelGGL(gemm3_f16, gg3, bs3, 0, stream, a0, a1, b0, b1, W1, W2);
    hipLaunchKernelGGL(softmax_add_kernel, dim3(TN), bs, 0, stream, W1, W2, p0);
    hipLaunchKernelGGL(gemm1_f16, gg1, bs, 0, stream, x0, v0, W1, W2);
    hipLaunchKernelGGL(cast1t_add_kernel, gt, bs, 0, stream, W1, W2, c0);
    hipLaunchKernelGGL(gemm1_f16, gg1, bs, 0, stream, p0, c0, W1, W2);
    hipLaunchKernelGGL(final_add_kernel, gelem, bs, 0, stream, W1, W2, out);
}